// Round 1
// baseline (5116.495 us; speedup 1.0000x reference)
//
#include <hip/hip_runtime.h>

#define DEV __device__ __forceinline__

typedef __attribute__((ext_vector_type(8))) short short8;
typedef __attribute__((ext_vector_type(4))) float floatx4;
typedef unsigned long long ull;
typedef __attribute__((ext_vector_type(2))) unsigned long long ull2;

static constexpr int B_ = 512, T_ = 912, H_ = 128, F_ = 32;
static constexpr size_t HN_OFF   = 1024;                       // bf16 hN[4][512][128]
static constexpr size_t XT_OFF   = HN_OFF + (size_t)4 * 512 * 128 * 2;   // 525312
static constexpr size_t RING_OFF = XT_OFF + (size_t)T_ * B_ * F_ * 2;    // 30409728
// ring per boundary-group: 8 chunks x 64KB (chunk = [8 slots][32 rows][256B])
static constexpr size_t RING_BPG = 8 * 65536;                  // 512 KB

template <int N> struct IC { static constexpr int value = N; };

DEV unsigned short bf16rne(float f) {
    unsigned u = __builtin_bit_cast(unsigned, f);
    u += 0x7FFFu + ((u >> 16) & 1u);
    return (unsigned short)(u >> 16);
}
DEV float bf16tof(unsigned short u) {
    return __builtin_bit_cast(float, ((unsigned)u) << 16);
}
DEV float fastsig(float y) {     // rcp(1+exp2(y))
    return __builtin_amdgcn_rcpf(1.f + __builtin_amdgcn_exp2f(y));
}
DEV float sigm(float x) { return fastsig(-1.44269504f * x); }
DEV unsigned ald(const unsigned* p) {
    return __hip_atomic_load(p, __ATOMIC_RELAXED, __HIP_MEMORY_SCOPE_AGENT);
}
DEV void ast32(unsigned* p, unsigned v) {
    __hip_atomic_store(p, v, __ATOMIC_RELAXED, __HIP_MEMORY_SCOPE_AGENT);
}
DEV ull ald8(const ull* p) {
    return __hip_atomic_load(p, __ATOMIC_RELAXED, __HIP_MEMORY_SCOPE_AGENT);
}
DEV void ast8(ull* p, ull v) {
    __hip_atomic_store(p, v, __ATOMIC_RELAXED, __HIP_MEMORY_SCOPE_AGENT);
}
DEV short8 ld_ring16(const char* p) {   // 16B A-frag piece from ring (L1-bypassing)
    ull2 r;
    r.x = ald8((const ull*)p);
    r.y = ald8((const ull*)(p + 8));
    return __builtin_bit_cast(short8, r);
}
DEV void bar_fast() {            // LDS-only barrier: no vmcnt drain
    asm volatile("s_waitcnt lgkmcnt(0)\n\ts_barrier" ::: "memory");
}

// ---------------------------------------------------------------------------
// x [B][T][32] fp32  ->  xT [T][B][32] bf16
__global__ __launch_bounds__(256) void xpose(const float* __restrict__ x,
                                             unsigned short* __restrict__ xT) {
    int tid = blockIdx.x * 256 + threadIdx.x;
    if (tid >= B_ * T_ * 4) return;
    int k = tid & 3;
    int r = tid >> 2;                                  // r = b*912 + t
    int b = r / T_;
    int t = r - b * T_;
    const float* p = x + ((size_t)r * 32 + k * 8);
    short8 v;
#pragma unroll
    for (int j = 0; j < 8; j++) v[j] = (short)bf16rne(p[j]);
    *(short8*)(xT + ((size_t)t * 512 + b) * 32 + k * 8) = v;
}

// ---------------------------------------------------------------------------
// Pipelined 4-layer LSTM scan. 64 blocks = 4 layers x 16 groups (32 samples).
// 32 samples/step amortizes the fixed per-step convoy cost (barrier, DS-pipe
// read storm, MFMA/trans dep chains, flag sync) over 2x the work.
// x A-fragments are loaded DIRECTLY from the inter-layer ring (global, sc0)
// into registers one step ahead: ring rows [row][256B] match the MFMA A-frag
// lane addressing, so the old ring->reg->LDS->reg staging (Xl) is gone.
__global__ __launch_bounds__(512, 2) void lstm_scan(
    const float* __restrict__ Wih0, const float* __restrict__ Whh0,
    const float* __restrict__ bih0, const float* __restrict__ bhh0,
    const float* __restrict__ Wih123, const float* __restrict__ Whh123,
    const float* __restrict__ bih123, const float* __restrict__ bhh123,
    char* __restrict__ ws) {
    const int tid  = threadIdx.x;
    const int wv   = tid >> 6;
    const int lane = tid & 63;
    const int col  = lane & 15;
    const int quad = lane >> 4;
    const int layer = blockIdx.x >> 4;
    const int grp   = blockIdx.x & 15;
    const int b0    = grp * 32;
    const bool lay0 = (layer == 0);

    unsigned* flags = (unsigned*)ws;                   // [4][16] chunks published
    unsigned* cons  = (unsigned*)(ws + 512);           // [4][16] chunks retired
    char* hN8 = ws + HN_OFF;
    const char* xTB = ws + XT_OFF;

    __shared__ unsigned short Ah[16][32][132];         // h history ring (slot = t&15)
    char* AhB = (char*)Ah;

    for (int i = tid; i < 16 * 32 * 132; i += 512) ((unsigned short*)Ah)[i] = 0;

    // ---- persistent weights, activation scale folded in ------------------
    short8 wh[4][4];
    short8 wx[4][4];
    float  bias_q[4];
    {
        const float *Wih, *Whh, *bih, *bhh;
        int kin, KX;
        if (layer == 0) { Wih = Wih0; Whh = Whh0; bih = bih0; bhh = bhh0; kin = 32; KX = 1; }
        else {
            Wih = Wih123 + (size_t)(layer - 1) * 512 * 128;
            Whh = Whh123 + (size_t)(layer - 1) * 512 * 128;
            bih = bih123 + (size_t)(layer - 1) * 512;
            bhh = bhh123 + (size_t)(layer - 1) * 512;
            kin = 128; KX = 4;
        }
#pragma unroll
        for (int q = 0; q < 4; q++) {
            const float sc = (q == 2) ? -2.88539008f : -1.44269504f;
            int row = q * 128 + wv * 16 + col;
            bias_q[q] = (bih[row] + bhh[row]) * sc;
#pragma unroll
            for (int kt = 0; kt < 4; kt++) {
                const float* ph = Whh + (size_t)row * 128 + kt * 32 + quad * 8;
                short8 v;
#pragma unroll
                for (int j = 0; j < 8; j++) v[j] = (short)bf16rne(ph[j] * sc);
                wh[q][kt] = v;
            }
#pragma unroll
            for (int kt = 0; kt < 4; kt++) {
                short8 v = {0, 0, 0, 0, 0, 0, 0, 0};
                if (kt < KX) {
                    const float* px = Wih + (size_t)row * kin + kt * 32 + quad * 8;
#pragma unroll
                    for (int j = 0; j < 8; j++) v[j] = (short)bf16rne(px[j] * sc);
                }
                wx[q][kt] = v;
            }
        }
    }

    unsigned* myflag   = &flags[layer * 16 + grp];
    unsigned* prevflag = &flags[(layer > 0 ? layer - 1 : 0) * 16 + grp];
    unsigned* mycons   = &cons[(layer > 0 ? layer - 1 : 0) * 16 + grp];
    unsigned* nextcons = &cons[layer * 16 + grp];
    char* prodRing = ws + RING_OFF + (size_t)(layer * 16 + grp) * RING_BPG;
    char* consRing = ws + RING_OFF + (size_t)((layer > 0 ? layer - 1 : 0) * 16 + grp) * RING_BPG;

    // precomputed byte offsets (constants through the whole kernel)
    const int ahrd  = col * 264 + quad * 16;                    // A-frag base in Ah
    const int hwr   = (quad * 4) * 264 + (wv * 16 + col) * 2;   // h write base
    const int exRow = tid >> 4;                                 // export row (0..31)
    const int exB   = (tid & 15) * 16;                          // export byte in row
    const int xroff = col * 256 + quad * 16;                    // ring A-frag lane off
    const int xoff0 = (b0 + col) * 64 + quad * 16;              // xT A-frag lane off

    const short8 z8 = {0, 0, 0, 0, 0, 0, 0, 0};
    short8 xb0[4], xb1[4];                                      // x A-frags for step t
#pragma unroll
    for (int kt = 0; kt < 4; kt++) { xb0[kt] = z8; xb1[kt] = z8; }
    unsigned pf = 0, pc = 0;
    float c8[8] = {0.f, 0.f, 0.f, 0.f, 0.f, 0.f, 0.f, 0.f};

    __syncthreads();                                   // LDS zeros visible

    // ---- prologue: x(0) into registers -----------------------------------
    if (!lay0) {
        if (tid == 0) { while (ald(prevflag) < 2u) {} }
        __syncthreads();
        const char* rb0 = consRing + xroff;            // chunk 0, slot 0
#pragma unroll
        for (int kt = 0; kt < 4; kt++) {
            xb0[kt] = ld_ring16(rb0 + kt * 64);
            xb1[kt] = ld_ring16(rb0 + 4096 + kt * 64);
        }
    } else {
        const char* px = xTB + xoff0;                  // t = 0
        xb0[0] = *(const short8*)px;
        xb1[0] = *(const short8*)(px + 1024);
    }

    int c = 0;
    auto step = [&](auto UC) {
        constexpr int u   = UC.value;
        constexpr bool bnd = (u == 0 || u == 8);
        constexpr bool stg = (u == 3 || u == 11);
        constexpr bool ver = (u == 7 || u == 15);
        constexpr int sph = (u < 8) ? 8 : 0;           // Ah slot base of chunk cc-1
        const int cc = c + (u >> 3);
        const int t  = cc * 8 + (u & 7);               // global timestep

        if (bnd) {
            if (tid == 0) {
                if (layer > 0 && cc <= 111) pf = ald(prevflag);
                if (layer < 3 && cc >= 8)   pc = ald(nextcons);
            }
            if (layer < 3 && cc >= 1) {                // burst chunk cc-1 -> ring
                char* rb = prodRing + (size_t)((cc - 1) & 7) * 65536 + exRow * 256 + exB;
                const char* src = AhB + sph * 8448 + exRow * 264 + exB;
#pragma unroll
                for (int p = 0; p < 8; p++) {
                    ull h0 = *(const ull*)(src + p * 8448);
                    ull h1 = *(const ull*)(src + p * 8448 + 8);
                    ast8((ull*)(rb + p * 8192), h0);
                    ast8((ull*)(rb + p * 8192 + 8), h1);
                }
            }
        }

        // ---- A fragments of h(t-1) (issued early; latency covered by x-MFMAs)
        const int slR = (u + 15) & 15;
        short8 ah0[4], ah1[4];
        const char* ab = AhB + slR * 8448 + ahrd;
#pragma unroll
        for (int kt = 0; kt < 4; kt++) {
            ah0[kt] = *(const short8*)(ab + kt * 64);
            ah1[kt] = *(const short8*)(ab + 4224 + kt * 64);
        }

        // ---- x-part: acc = bias + x(t)*Wx ---------------------------------
        floatx4 acc[4][2];
#pragma unroll
        for (int q = 0; q < 4; q++) {
            floatx4 a = {bias_q[q], bias_q[q], bias_q[q], bias_q[q]};
            acc[q][0] = a; acc[q][1] = a;
        }
        if (lay0) {                                    // kt 1..3 weights are zero
#pragma unroll
            for (int q = 0; q < 4; q++) {
                acc[q][0] = __builtin_amdgcn_mfma_f32_16x16x32_bf16(xb0[0], wx[q][0], acc[q][0], 0, 0, 0);
                acc[q][1] = __builtin_amdgcn_mfma_f32_16x16x32_bf16(xb1[0], wx[q][0], acc[q][1], 0, 0, 0);
            }
        } else {
#pragma unroll
            for (int kt = 0; kt < 4; kt++)
#pragma unroll
                for (int q = 0; q < 4; q++) {
                    acc[q][0] = __builtin_amdgcn_mfma_f32_16x16x32_bf16(xb0[kt], wx[q][kt], acc[q][0], 0, 0, 0);
                    acc[q][1] = __builtin_amdgcn_mfma_f32_16x16x32_bf16(xb1[kt], wx[q][kt], acc[q][1], 0, 0, 0);
                }
        }

        // ---- reload xb with x(t+1); lands during rec-MFMAs + gates --------
        if (t < 911) {
            if (lay0) {
                const char* px = xTB + (size_t)(t + 1) * 32768 + xoff0;
                xb0[0] = *(const short8*)px;
                xb1[0] = *(const short8*)(px + 1024);
            } else {
                const char* rb2 = consRing + (size_t)(((t + 1) >> 3) & 7) * 65536
                                  + (size_t)((t + 1) & 7) * 8192 + xroff;
#pragma unroll
                for (int kt = 0; kt < 4; kt++) {
                    xb0[kt] = ld_ring16(rb2 + kt * 64);
                    xb1[kt] = ld_ring16(rb2 + 4096 + kt * 64);
                }
            }
        }

        // ---- recurrent part: acc += h(t-1)*Wh -----------------------------
#pragma unroll
        for (int kt = 0; kt < 4; kt++)
#pragma unroll
            for (int q = 0; q < 4; q++) {
                acc[q][0] = __builtin_amdgcn_mfma_f32_16x16x32_bf16(ah0[kt], wh[q][kt], acc[q][0], 0, 0, 0);
                acc[q][1] = __builtin_amdgcn_mfma_f32_16x16x32_bf16(ah1[kt], wh[q][kt], acc[q][1], 0, 0, 0);
            }

        // ---- gates, c/h update, h(t) -> Ah slot u -------------------------
        char* hb = AhB + (u & 15) * 8448 + hwr;
#pragma unroll
        for (int rt = 0; rt < 2; rt++)
#pragma unroll
            for (int r = 0; r < 4; r++) {
                float iv = fastsig(acc[0][rt][r]);
                float fv = fastsig(acc[1][rt][r]);
                float gr = fastsig(acc[2][rt][r]);     // (tanh(g)+1)/2
                float ov = fastsig(acc[3][rt][r]);
                float gt = 2.f * gr - 1.f;
                const int ci = rt * 4 + r;
                float cv = fv * c8[ci] + iv * gt;
                c8[ci] = cv;
                float rc = fastsig(-2.88539008f * cv);
                float hv = ov * (2.f * rc - 1.f);
                *(unsigned short*)(hb + rt * 4224 + r * 264) = bf16rne(hv);
            }

        if (stg) {
            __syncthreads();                           // full drain: release point
            if (tid == 0) {
                if (layer < 3 && cc >= 1) ast32(myflag, (unsigned)cc);
                if (layer > 0) ast32(mycons, (unsigned)cc);   // chunks <= cc-1 retired
            }
        } else {
            if (ver && tid == 0) {
                if (layer > 0 && cc <= 111) {
                    unsigned tgt = cc + 3;
                    if (pf < tgt) while (ald(prevflag) < tgt) {}
                }
                if (layer < 3 && cc >= 8) {
                    unsigned tgt = cc - 7;
                    if (pc < tgt) while (ald(nextcons) < tgt) {}
                }
            }
            bar_fast();
        }
    };

    for (c = 0; c < 114; c += 2) {
        step(IC<0>{});  step(IC<1>{});  step(IC<2>{});  step(IC<3>{});
        step(IC<4>{});  step(IC<5>{});  step(IC<6>{});  step(IC<7>{});
        step(IC<8>{});  step(IC<9>{});  step(IC<10>{}); step(IC<11>{});
        step(IC<12>{}); step(IC<13>{}); step(IC<14>{}); step(IC<15>{});
    }

    // ---- epilogue: burst chunk 113 (slots 8..15), publish, export hN -----
    if (layer < 3) {
        char* rb = prodRing + (size_t)(113 & 7) * 65536 + exRow * 256 + exB;
        const char* src = AhB + 8 * 8448 + exRow * 264 + exB;
#pragma unroll
        for (int p = 0; p < 8; p++) {
            ull h0 = *(const ull*)(src + p * 8448);
            ull h1 = *(const ull*)(src + p * 8448 + 8);
            ast8((ull*)(rb + p * 8192), h0);
            ast8((ull*)(rb + p * 8192 + 8), h1);
        }
    }
    __syncthreads();                                   // drain ring stores
    if (tid == 0 && layer < 3) ast32(myflag, 114u);
    {
        const char* src = AhB + 15 * 8448 + exRow * 264 + exB;   // h[911]
        ull h0 = *(const ull*)src;
        ull h1 = *(const ull*)(src + 8);
        char* dst = hN8 + ((size_t)layer * 512 + b0 + exRow) * 256 + exB;
        *(ull*)dst = h0;
        *(ull*)(dst + 8) = h1;
    }
}

// ---------------------------------------------------------------------------
// heads: hN [4][512][128] bf16 -> opt/tp/sl/lot, each [4][512][4] fp32
__global__ __launch_bounds__(256) void heads(
    const unsigned short* __restrict__ hN,
    const float* __restrict__ Wopt, const float* __restrict__ bopt,
    const float* __restrict__ Wlot, const float* __restrict__ blot,
    const float* __restrict__ Wtp,  const float* __restrict__ btp,
    const float* __restrict__ Wsl,  const float* __restrict__ bsl,
    float* __restrict__ out) {
    int tid = blockIdx.x * 256 + threadIdx.x;
    if (tid >= 4 * 4 * 512) return;
    int b  = tid & 511;
    int l  = (tid >> 9) & 3;
    int hd = tid >> 11;
    const float *W, *bb;
    if      (hd == 0) { W = Wopt; bb = bopt; }
    else if (hd == 1) { W = Wtp;  bb = btp;  }
    else if (hd == 2) { W = Wsl;  bb = bsl;  }
    else              { W = Wlot; bb = blot; }
    const unsigned short* h = hN + ((size_t)l * 512 + b) * 128;
    float z0 = bb[0], z1 = bb[1], z2 = bb[2], z3 = bb[3];
    for (int i = 0; i < 128; i++) {
        float hv = bf16tof(h[i]);
        z0 += hv * W[0 * 128 + i];
        z1 += hv * W[1 * 128 + i];
        z2 += hv * W[2 * 128 + i];
        z3 += hv * W[3 * 128 + i];
    }
    float o0, o1, o2, o3;
    if (hd == 0) {
        float m = fmaxf(fmaxf(z0, z1), fmaxf(z2, z3));
        float e0 = __builtin_amdgcn_exp2f((z0 - m) * 1.44269504f);
        float e1 = __builtin_amdgcn_exp2f((z1 - m) * 1.44269504f);
        float e2 = __builtin_amdgcn_exp2f((z2 - m) * 1.44269504f);
        float e3 = __builtin_amdgcn_exp2f((z3 - m) * 1.44269504f);
        float rs = __builtin_amdgcn_rcpf(e0 + e1 + e2 + e3);
        float p0 = e0 * rs, p1 = e1 * rs, p2 = e2 * rs, p3 = e3 * rs;
        float m2 = fmaxf(fmaxf(p0, p1), fmaxf(p2, p3));
        float f0 = __builtin_amdgcn_exp2f((p0 - m2) * 1.44269504f);
        float f1 = __builtin_amdgcn_exp2f((p1 - m2) * 1.44269504f);
        float f2 = __builtin_amdgcn_exp2f((p2 - m2) * 1.44269504f);
        float f3 = __builtin_amdgcn_exp2f((p3 - m2) * 1.44269504f);
        float rs2 = __builtin_amdgcn_rcpf(f0 + f1 + f2 + f3);
        o0 = f0 * rs2; o1 = f1 * rs2; o2 = f2 * rs2; o3 = f3 * rs2;
    } else {
        o0 = sigm(sigm(z0)); o1 = sigm(sigm(z1));
        o2 = sigm(sigm(z2)); o3 = sigm(sigm(z3));
    }
    float* o = out + (size_t)hd * 8192 + ((size_t)l * 512 + b) * 4;
    o[0] = o0; o[1] = o1; o[2] = o2; o[3] = o3;
}

// ---------------------------------------------------------------------------
extern "C" void kernel_launch(void* const* d_in, const int* in_sizes, int n_in,
                              void* d_out, int out_size, void* d_ws, size_t ws_size,
                              hipStream_t stream) {
    (void)in_sizes; (void)n_in; (void)out_size; (void)ws_size;
    const float* x      = (const float*)d_in[0];
    const float* Wih0   = (const float*)d_in[1];
    const float* Whh0   = (const float*)d_in[2];
    const float* bih0   = (const float*)d_in[3];
    const float* bhh0   = (const float*)d_in[4];
    const float* Wih123 = (const float*)d_in[5];
    const float* Whh123 = (const float*)d_in[6];
    const float* bih123 = (const float*)d_in[7];
    const float* bhh123 = (const float*)d_in[8];
    const float* Wopt = (const float*)d_in[9];
    const float* bopt = (const float*)d_in[10];
    const float* Wlot = (const float*)d_in[11];
    const float* blot = (const float*)d_in[12];
    const float* Wtp  = (const float*)d_in[13];
    const float* btp  = (const float*)d_in[14];
    const float* Wsl  = (const float*)d_in[15];
    const float* bsl  = (const float*)d_in[16];
    char* ws = (char*)d_ws;

    hipMemsetAsync(ws, 0, 1024, stream);               // flags + cons
    xpose<<<(B_ * T_ * 4 + 255) / 256, 256, 0, stream>>>(x, (unsigned short*)(ws + XT_OFF));
    lstm_scan<<<64, 512, 0, stream>>>(Wih0, Whh0, bih0, bhh0,
                                      Wih123, Whh123, bih123, bhh123, ws);
    heads<<<32, 256, 0, stream>>>((const unsigned short*)(ws + HN_OFF),
                                  Wopt, bopt, Wlot, blot, Wtp, btp, Wsl, bsl,
                                  (float*)d_out);
}